// Round 6
// baseline (169.985 us; speedup 1.0000x reference)
//
#include <hip/hip_runtime.h>
#include <hip/hip_bf16.h>
#include <cstdint>

#define EPS 1e-5f
#define PATH_COEFF 0.04419417382415922f   // 1/sqrt(512)
#define CG110     0.5773502691896258f     // 1/sqrt(3)

typedef __bf16 v8bf __attribute__((ext_vector_type(8)));
typedef float  v4f  __attribute__((ext_vector_type(4)));
typedef _Float16 v4h __attribute__((ext_vector_type(4)));

static __device__ __forceinline__ unsigned short f2bf(float x){
    unsigned int u = __builtin_bit_cast(unsigned int, x);
    u += 0x7fffu + ((u >> 16) & 1u);      // RNE
    return (unsigned short)(u >> 16);
}
static __device__ __forceinline__ unsigned short f2h(float x){
    return __builtin_bit_cast(unsigned short, (_Float16)x);
}

// ---------------------------------------------------------------------------
// K0: fused prep. blocks [0,260): we_w2/we_b2 -> Vt2 frag-major (8KB LDS);
// [260,264): om_w1 -> w1t bf16 transpose; [264,776): per-row prep, wave/row.
// ---------------------------------------------------------------------------
__global__ __launch_bounds__(256)
void k_pre(const float* __restrict__ w2, const float* __restrict__ b2,
           unsigned short* __restrict__ Vt2,
           const float* __restrict__ om_w1, unsigned short* __restrict__ w1t,
           const float* __restrict__ x, const float* __restrict__ lng,
           const float* __restrict__ lnb, const float* __restrict__ we_w1,
           unsigned short* __restrict__ Q2, float* __restrict__ Ht, int N)
{
    __shared__ __align__(16) unsigned short tile[32][128];   // 8 KB
    int b = blockIdx.x;
    int t = threadIdx.x;

    if (b < 260){
        // ---- convV: Vt2[k][ps16][quad4][w128][8p] bf16 ----
        int k    = b >> 2;
        int slab = b & 3;
        const float* srcbase = (k < 64) ? (w2 + (size_t)k * 65536) : b2;
        for (int chunk = 0; chunk < 4; ++chunk){
            int pbase = slab*128 + chunk*32;
            #pragma unroll
            for (int i = 0; i < 4; ++i){
                int g = t + 256*i;
                int ploc = g >> 5, c4 = g & 31;
                const float4 v = *(const float4*)(srcbase + (size_t)(pbase + ploc)*128 + c4*4);
                unsigned int w0 = (unsigned)f2bf(v.x) | ((unsigned)f2bf(v.y) << 16);
                unsigned int w1 = (unsigned)f2bf(v.z) | ((unsigned)f2bf(v.w) << 16);
                *(uint2*)&tile[ploc][c4*4] = make_uint2(w0, w1);
            }
            __syncthreads();
            int w = t & 127, h = t >> 7;
            int ps = slab*4 + chunk;
            unsigned int words[8];
            #pragma unroll
            for (int g2 = 0; g2 < 8; ++g2)
                words[g2] = (unsigned)tile[h*16 + g2*2][w] | ((unsigned)tile[h*16 + g2*2 + 1][w] << 16);
            unsigned short* dq0 = Vt2 + (((size_t)(k*16 + ps)*4 + 2*h    )*128 + w)*8;
            unsigned short* dq1 = Vt2 + (((size_t)(k*16 + ps)*4 + 2*h + 1)*128 + w)*8;
            *(uint4*)dq0 = make_uint4(words[0], words[1], words[2], words[3]);
            *(uint4*)dq1 = make_uint4(words[4], words[5], words[6], words[7]);
            __syncthreads();
        }
    } else if (b < 264){
        // ---- convW: w1t[j512][w128] bf16 = om_w1[w][j] ----
        int j0 = (b - 260) * 128;
        for (int chunk = 0; chunk < 4; ++chunk){
            #pragma unroll
            for (int i = 0; i < 4; ++i){
                int g = t + 256*i;
                int wloc = g >> 5, c4 = g & 31;
                int w = chunk*32 + wloc;
                const float4 v = *(const float4*)(om_w1 + (size_t)w*512 + j0 + c4*4);
                unsigned int a = (unsigned)f2bf(v.x) | ((unsigned)f2bf(v.y) << 16);
                unsigned int bb = (unsigned)f2bf(v.z) | ((unsigned)f2bf(v.w) << 16);
                *(uint2*)&tile[wloc][c4*4] = make_uint2(a, bb);
            }
            __syncthreads();
            int jl = t & 127, h = t >> 7;
            unsigned int words[8];
            #pragma unroll
            for (int g2 = 0; g2 < 8; ++g2)
                words[g2] = (unsigned)tile[h*16 + g2*2][jl] | ((unsigned)tile[h*16 + g2*2 + 1][jl] << 16);
            unsigned short* dst = w1t + (size_t)(j0 + jl)*128 + chunk*32 + h*16;
            *(uint4*)dst       = make_uint4(words[0], words[1], words[2], words[3]);
            *(uint4*)(dst + 8) = make_uint4(words[4], words[5], words[6], words[7]);
            __syncthreads();
        }
    } else {
        // ---- prep: wave per row, 4 rows/block ----
        int wv = t >> 6, lane = t & 63;
        int row = (b - 264)*4 + wv;
        const float* xr = x + (size_t)row * 64;
        float f[16]; float mu = 0.f;
        #pragma unroll
        for (int u = 0; u < 16; ++u){ f[u] = xr[u]; mu += f[u]; }
        mu *= (1.f/16.f);
        float var = 0.f;
        #pragma unroll
        for (int u = 0; u < 16; ++u){ float d = f[u] - mu; var += d*d; }
        var *= (1.f/16.f);
        float inv = rsqrtf(var + EPS);
        float lnf[16];
        #pragma unroll
        for (int u = 0; u < 16; ++u) lnf[u] = (f[u]-mu)*inv*lng[u] + lnb[u];
        float h1 = 0.f;
        #pragma unroll
        for (int u = 0; u < 16; ++u) h1 += lnf[u] * we_w1[u*64 + lane];
        float h = h1 / (1.f + expf(-h1));
        Ht[(size_t)lane * N + row] = h;
        if (lane == 0) Ht[(size_t)64 * N + row] = 1.f;

        union { unsigned short qs[8]; uint4 v; } qu;
        #pragma unroll
        for (int j = 0; j < 8; ++j){
            int p = lane*8 + j;
            float q;
            if (p < 256){
                int u = p >> 4, v = p & 15;
                q = PATH_COEFF * f[u] * f[v];
            } else {
                int pp = p - 256;
                int u = pp >> 4, v = pp & 15;
                const float* ya = xr + 16 + u*3;
                const float* yb = xr + 16 + v*3;
                q = (PATH_COEFF * CG110) * (ya[0]*yb[0] + ya[1]*yb[1] + ya[2]*yb[2]);
            }
            qu.qs[j] = f2bf(q);
        }
        int rb = row >> 6, r64 = row & 63;
        int ps = lane >> 2, quad4 = lane & 3;
        *(uint4*)(Q2 + (((size_t)(rb*16 + ps)*4 + quad4)*64 + r64)*8) = qu.v;
    }
}

// ---------------------------------------------------------------------------
// K1: partial[k][n][w] (fp16) = H[n,k] * sum_p Q[n,p] V[k,p,w]
// Block = (k, mb-pair). B k-slice staged through LDS in two 64KB halves ->
// guaranteed CU-local reuse (no XCD-mapping assumption). A (Q2, 2MB, hot in
// every XCD L2) loaded in 16-load chunks. acc[2 mb][4][4] = 128 VGPR.
// lb(256,2): 2 blocks/CU (LDS 64KB). Epilogue reuses Bs after final barrier.
// ---------------------------------------------------------------------------
__global__ __launch_bounds__(256, 2)
void k_main(const unsigned short* __restrict__ Q2, const unsigned short* __restrict__ Vt2,
            const float* __restrict__ Ht, unsigned short* __restrict__ partial, int N)
{
    __shared__ __align__(16) unsigned short Bs[32768];   // 64 KB
    int kb = blockIdx.x % 65;
    int g  = blockIdx.x / 65;          // mb pair: g*2, g*2+1

    int tid  = threadIdx.x;
    int lane = tid & 63, wv = tid >> 6;
    int r2 = wv >> 1, c2 = wv & 1;
    int quad = lane >> 4, l16 = lane & 15;
    int wbase = c2*64;

    v4f acc[2][4][4];
    #pragma unroll
    for (int mi=0;mi<2;++mi)
      #pragma unroll
      for (int m=0;m<4;++m)
        #pragma unroll
        for (int n=0;n<4;++n)
          #pragma unroll
          for (int r=0;r<4;++r) acc[mi][m][n][r] = 0.f;

    const unsigned short* bsrc = Vt2 + (size_t)kb*65536;

    for (int half = 0; half < 2; ++half){
        __syncthreads();
        // stage 64 KB: 4096 uint4 / 256 thr = 16 each, fully coalesced
        const uint4* s4 = (const uint4*)(bsrc + half*32768);
        uint4* d4 = (uint4*)Bs;
        #pragma unroll
        for (int i = 0; i < 16; ++i)
            d4[tid + i*256] = s4[tid + i*256];
        __syncthreads();

        #pragma unroll
        for (int mi = 0; mi < 2; ++mi){
            int rowbase = (g*2 + mi)*128 + r2*64;
            int rb = rowbase >> 6;
            const unsigned short* aroot = Q2 + (size_t)rb*32768 + half*16384 + quad*512 + l16*8;
            #pragma unroll
            for (int pc = 0; pc < 2; ++pc){
                v8bf a[4][4];
                #pragma unroll
                for (int ps = 0; ps < 4; ++ps)
                    #pragma unroll
                    for (int m = 0; m < 4; ++m)
                        a[ps][m] = *(const v8bf*)(aroot + (pc*4 + ps)*2048 + m*128);
                #pragma unroll
                for (int ps = 0; ps < 4; ++ps){
                    int ps8 = pc*4 + ps;
                    const unsigned short* bp = Bs + ((ps8*4 + quad)*128 + wbase + l16)*8;
                    v8bf bb[4];
                    #pragma unroll
                    for (int n = 0; n < 4; ++n) bb[n] = *(const v8bf*)(bp + n*128);
                    #pragma unroll
                    for (int m = 0; m < 4; ++m)
                      #pragma unroll
                      for (int n = 0; n < 4; ++n)
                        acc[mi][m][n] = __builtin_amdgcn_mfma_f32_16x16x32_bf16(a[ps][m], bb[n], acc[mi][m][n], 0, 0, 0);
                }
            }
        }
    }

    // epilogue: wave-private transpose in (now-free) Bs, dense 128B-row stores
    __syncthreads();
    unsigned short* Es = Bs + wv*1056;     // 16 rows x 66 pitch
    #pragma unroll
    for (int mi = 0; mi < 2; ++mi){
        int rowbase = (g*2 + mi)*128 + r2*64;
        const float* hp = Ht + (size_t)kb*N + rowbase + quad*4;
        #pragma unroll
        for (int m = 0; m < 4; ++m){
            v4f hv = *(const v4f*)(hp + m*16);
            #pragma unroll
            for (int n = 0; n < 4; ++n)
              #pragma unroll
              for (int r = 0; r < 4; ++r)
                Es[(quad*4 + r)*66 + n*16 + l16] = f2h(hv[r]*acc[mi][m][n][r]);
            unsigned short* gp = partial + (size_t)kb*N*128 + (size_t)(rowbase + m*16)*128 + wbase;
            #pragma unroll
            for (int jj = 0; jj < 2; ++jj){
                int idx = lane*2 + jj;
                int rr = idx >> 3, cc = idx & 7;
                *(uint4*)(gp + (size_t)rr*128 + cc*8) = *(const uint4*)(Es + rr*66 + cc*8);
            }
        }
    }
}

// ---------------------------------------------------------------------------
// K2: reduce 65 fp16 slices + LayerNorm(128) -> lnf bf16. 4 rows/block,
// 128 thr: thread owns (row = t>>5, w = (t&31)*4). Dense 8B loads.
// ---------------------------------------------------------------------------
__global__ __launch_bounds__(128)
void k_red(const unsigned short* __restrict__ partial, const float* __restrict__ g,
           const float* __restrict__ b, unsigned short* __restrict__ lnf, int N)
{
    int t = threadIdx.x;
    int row0 = blockIdx.x * 4;
    int rl = t >> 5, w = (t & 31)*4;
    int row = row0 + rl;

    const unsigned short* p0 = partial + (size_t)row*128 + w;
    float s0=0.f, s1=0.f, s2=0.f, s3=0.f;
    #pragma unroll
    for (int sl = 0; sl < 65; ++sl){
        v4h v = *(const v4h*)(p0 + (size_t)sl*N*128);
        s0 += (float)v[0]; s1 += (float)v[1]; s2 += (float)v[2]; s3 += (float)v[3];
    }
    float sum = s0+s1+s2+s3;
    float sq  = s0*s0+s1*s1+s2*s2+s3*s3;
    #pragma unroll
    for (int off=16; off>0; off>>=1){
        sum += __shfl_xor(sum, off, 32);
        sq  += __shfl_xor(sq,  off, 32);
    }
    float mu  = sum * (1.f/128.f);
    float var = sq * (1.f/128.f) - mu*mu;
    float inv = rsqrtf(var + EPS);
    unsigned short o[4];
    o[0] = f2bf((s0-mu)*inv*g[w+0] + b[w+0]);
    o[1] = f2bf((s1-mu)*inv*g[w+1] + b[w+1]);
    o[2] = f2bf((s2-mu)*inv*g[w+2] + b[w+2]);
    o[3] = f2bf((s3-mu)*inv*g[w+3] + b[w+3]);
    *(uint2*)(lnf + (size_t)row*128 + w) = *(uint2*)o;
}

// ---------------------------------------------------------------------------
// K3: out[n] = silu(lnf @ om_w1) @ om_w2 + om_b2. 32 blocks x 64 rows,
// 4 waves, wave wv owns j-range [wv*128, +128): 4x8 MFMA tiles. LDS reduce.
// ---------------------------------------------------------------------------
__global__ __launch_bounds__(256)
void k_mlp2(const unsigned short* __restrict__ lnf, const unsigned short* __restrict__ w1t,
            const float* __restrict__ w2, const float* __restrict__ b2,
            float* __restrict__ out, int N)
{
    __shared__ float red2[4][64];
    int tid = threadIdx.x, lane = tid & 63, wv = tid >> 6;
    int quad = lane >> 4, l16 = lane & 15;
    int rowbase = blockIdx.x * 64;
    int jbase = wv * 128;

    v4f acc[4][8];
    #pragma unroll
    for (int m=0;m<4;++m)
      #pragma unroll
      for (int n=0;n<8;++n)
        #pragma unroll
        for (int r=0;r<4;++r) acc[m][n][r] = 0.f;

    #pragma unroll
    for (int ps = 0; ps < 4; ++ps){
        v8bf a[4], bb[8];
        #pragma unroll
        for (int m=0;m<4;++m)
            a[m]  = *(const v8bf*)(lnf + (size_t)(rowbase + m*16 + l16)*128 + ps*32 + quad*8);
        #pragma unroll
        for (int n=0;n<8;++n)
            bb[n] = *(const v8bf*)(w1t + (size_t)(jbase + n*16 + l16)*128 + ps*32 + quad*8);
        #pragma unroll
        for (int m=0;m<4;++m)
          #pragma unroll
          for (int n=0;n<8;++n)
            acc[m][n] = __builtin_amdgcn_mfma_f32_16x16x32_bf16(a[m], bb[n], acc[m][n], 0, 0, 0);
    }

    float w2v[8];
    #pragma unroll
    for (int n=0;n<8;++n) w2v[n] = w2[jbase + n*16 + l16];

    #pragma unroll
    for (int m=0;m<4;++m){
        #pragma unroll
        for (int r=0;r<4;++r){
            float s = 0.f;
            #pragma unroll
            for (int n=0;n<8;++n){
                float v = acc[m][n][r];
                s += (v / (1.f + expf(-v))) * w2v[n];
            }
            #pragma unroll
            for (int off=8; off>0; off>>=1) s += __shfl_xor(s, off, 16);
            if (l16 == 0) red2[wv][m*16 + quad*4 + r] = s;
        }
    }
    __syncthreads();
    if (tid < 64)
        out[rowbase + tid] = red2[0][tid] + red2[1][tid] + red2[2][tid] + red2[3][tid] + b2[0];
}

// ---------------------------------------------------------------------------
extern "C" void kernel_launch(void* const* d_in, const int* in_sizes, int n_in,
                              void* d_out, int out_size, void* d_ws, size_t ws_size,
                              hipStream_t stream)
{
    const float* x     = (const float*)d_in[0];
    const float* we_g  = (const float*)d_in[1];
    const float* we_b  = (const float*)d_in[2];
    const float* we_w1 = (const float*)d_in[3];
    const float* we_w2 = (const float*)d_in[4];
    const float* we_b2 = (const float*)d_in[5];
    const float* om_g  = (const float*)d_in[6];
    const float* om_b  = (const float*)d_in[7];
    const float* om_w1 = (const float*)d_in[8];
    const float* om_w2 = (const float*)d_in[9];
    const float* om_b2 = (const float*)d_in[10];

    int N  = in_sizes[0] / 64;     // 2048

    char* ws = (char*)d_ws;
    size_t offV = 0;
    size_t szV  = (size_t)65*16*4*128*8*2;       // 8,519,680
    size_t offQ = offV + szV;
    size_t szQ  = (size_t)N*512*2;               // 2 MB
    size_t offH = offQ + szQ;
    size_t szH  = (size_t)65*N*4;
    size_t offP = offH + szH;
    size_t szP  = (size_t)65*N*128*2;            // 34 MB fp16
    size_t offL = offP + szP;
    size_t szL  = (size_t)N*128*2;
    size_t offW = offL + szL;                    // +128 KB

    unsigned short* Vt2 = (unsigned short*)(ws + offV);
    unsigned short* Q2  = (unsigned short*)(ws + offQ);
    float* Ht           = (float*)(ws + offH);
    unsigned short* Par = (unsigned short*)(ws + offP);
    unsigned short* Lnf = (unsigned short*)(ws + offL);
    unsigned short* W1t = (unsigned short*)(ws + offW);
    float* out = (float*)d_out;

    hipLaunchKernelGGL(k_pre,  dim3(264 + N/4), dim3(256), 0, stream,
                       we_w2, we_b2, Vt2, om_w1, W1t, x, we_g, we_b, we_w1, Q2, Ht, N);
    hipLaunchKernelGGL(k_main, dim3(65*8),      dim3(256), 0, stream, Q2, Vt2, Ht, Par, N);
    hipLaunchKernelGGL(k_red,  dim3(N/4),       dim3(128), 0, stream, Par, om_g, om_b, Lnf, N);
    hipLaunchKernelGGL(k_mlp2, dim3(N/64),      dim3(256), 0, stream, Lnf, W1t, om_w2, om_b2, out, N);
}

// Round 8
// 151.886 us; speedup vs baseline: 1.1192x; 1.1192x over previous
//
#include <hip/hip_runtime.h>
#include <hip/hip_bf16.h>
#include <cstdint>

#define EPS 1e-5f
#define PATH_COEFF 0.04419417382415922f   // 1/sqrt(512)
#define CG110     0.5773502691896258f     // 1/sqrt(3)

typedef __bf16 v8bf __attribute__((ext_vector_type(8)));
typedef float  v4f  __attribute__((ext_vector_type(4)));
typedef _Float16 v4h __attribute__((ext_vector_type(4)));
typedef unsigned int v4u __attribute__((ext_vector_type(4)));
typedef unsigned int v2u __attribute__((ext_vector_type(2)));

static __device__ __forceinline__ unsigned short f2bf(float x){
    unsigned int u = __builtin_bit_cast(unsigned int, x);
    u += 0x7fffu + ((u >> 16) & 1u);      // RNE
    return (unsigned short)(u >> 16);
}
static __device__ __forceinline__ unsigned short f2h(float x){
    return __builtin_bit_cast(unsigned short, (_Float16)x);
}

// ---------------------------------------------------------------------------
// K0: fused prep. blocks [0,260): we_w2/we_b2 -> Vt2 frag-major (8KB LDS);
// [260,264): om_w1 -> w1t bf16 transpose; [264,776): per-row prep, wave/row.
// ---------------------------------------------------------------------------
__global__ __launch_bounds__(256)
void k_pre(const float* __restrict__ w2, const float* __restrict__ b2,
           unsigned short* __restrict__ Vt2,
           const float* __restrict__ om_w1, unsigned short* __restrict__ w1t,
           const float* __restrict__ x, const float* __restrict__ lng,
           const float* __restrict__ lnb, const float* __restrict__ we_w1,
           unsigned short* __restrict__ Q2, float* __restrict__ Ht, int N)
{
    __shared__ __align__(16) unsigned short tile[32][128];   // 8 KB
    int b = blockIdx.x;
    int t = threadIdx.x;

    if (b < 260){
        // ---- convV: Vt2[k][ps16][quad4][w128][8p] bf16 ----
        int k    = b >> 2;
        int slab = b & 3;
        const float* srcbase = (k < 64) ? (w2 + (size_t)k * 65536) : b2;
        for (int chunk = 0; chunk < 4; ++chunk){
            int pbase = slab*128 + chunk*32;
            #pragma unroll
            for (int i = 0; i < 4; ++i){
                int g = t + 256*i;
                int ploc = g >> 5, c4 = g & 31;
                const float4 v = *(const float4*)(srcbase + (size_t)(pbase + ploc)*128 + c4*4);
                unsigned int w0 = (unsigned)f2bf(v.x) | ((unsigned)f2bf(v.y) << 16);
                unsigned int w1 = (unsigned)f2bf(v.z) | ((unsigned)f2bf(v.w) << 16);
                *(uint2*)&tile[ploc][c4*4] = make_uint2(w0, w1);
            }
            __syncthreads();
            int w = t & 127, h = t >> 7;
            int ps = slab*4 + chunk;
            unsigned int words[8];
            #pragma unroll
            for (int g2 = 0; g2 < 8; ++g2)
                words[g2] = (unsigned)tile[h*16 + g2*2][w] | ((unsigned)tile[h*16 + g2*2 + 1][w] << 16);
            unsigned short* dq0 = Vt2 + (((size_t)(k*16 + ps)*4 + 2*h    )*128 + w)*8;
            unsigned short* dq1 = Vt2 + (((size_t)(k*16 + ps)*4 + 2*h + 1)*128 + w)*8;
            *(uint4*)dq0 = make_uint4(words[0], words[1], words[2], words[3]);
            *(uint4*)dq1 = make_uint4(words[4], words[5], words[6], words[7]);
            __syncthreads();
        }
    } else if (b < 264){
        // ---- convW: w1t[j512][w128] bf16 = om_w1[w][j] ----
        int j0 = (b - 260) * 128;
        for (int chunk = 0; chunk < 4; ++chunk){
            #pragma unroll
            for (int i = 0; i < 4; ++i){
                int g = t + 256*i;
                int wloc = g >> 5, c4 = g & 31;
                int w = chunk*32 + wloc;
                const float4 v = *(const float4*)(om_w1 + (size_t)w*512 + j0 + c4*4);
                unsigned int a = (unsigned)f2bf(v.x) | ((unsigned)f2bf(v.y) << 16);
                unsigned int bb = (unsigned)f2bf(v.z) | ((unsigned)f2bf(v.w) << 16);
                *(uint2*)&tile[wloc][c4*4] = make_uint2(a, bb);
            }
            __syncthreads();
            int jl = t & 127, h = t >> 7;
            unsigned int words[8];
            #pragma unroll
            for (int g2 = 0; g2 < 8; ++g2)
                words[g2] = (unsigned)tile[h*16 + g2*2][jl] | ((unsigned)tile[h*16 + g2*2 + 1][jl] << 16);
            unsigned short* dst = w1t + (size_t)(j0 + jl)*128 + chunk*32 + h*16;
            *(uint4*)dst       = make_uint4(words[0], words[1], words[2], words[3]);
            *(uint4*)(dst + 8) = make_uint4(words[4], words[5], words[6], words[7]);
            __syncthreads();
        }
    } else {
        // ---- prep: wave per row, 4 rows/block ----
        int wv = t >> 6, lane = t & 63;
        int row = (b - 264)*4 + wv;
        const float* xr = x + (size_t)row * 64;
        float f[16]; float mu = 0.f;
        #pragma unroll
        for (int u = 0; u < 16; ++u){ f[u] = xr[u]; mu += f[u]; }
        mu *= (1.f/16.f);
        float var = 0.f;
        #pragma unroll
        for (int u = 0; u < 16; ++u){ float d = f[u] - mu; var += d*d; }
        var *= (1.f/16.f);
        float inv = rsqrtf(var + EPS);
        float lnf[16];
        #pragma unroll
        for (int u = 0; u < 16; ++u) lnf[u] = (f[u]-mu)*inv*lng[u] + lnb[u];
        float h1 = 0.f;
        #pragma unroll
        for (int u = 0; u < 16; ++u) h1 += lnf[u] * we_w1[u*64 + lane];
        float h = h1 / (1.f + expf(-h1));
        Ht[(size_t)lane * N + row] = h;
        if (lane == 0) Ht[(size_t)64 * N + row] = 1.f;

        union { unsigned short qs[8]; uint4 v; } qu;
        #pragma unroll
        for (int j = 0; j < 8; ++j){
            int p = lane*8 + j;
            float q;
            if (p < 256){
                int u = p >> 4, v = p & 15;
                q = PATH_COEFF * f[u] * f[v];
            } else {
                int pp = p - 256;
                int u = pp >> 4, v = pp & 15;
                const float* ya = xr + 16 + u*3;
                const float* yb = xr + 16 + v*3;
                q = (PATH_COEFF * CG110) * (ya[0]*yb[0] + ya[1]*yb[1] + ya[2]*yb[2]);
            }
            qu.qs[j] = f2bf(q);
        }
        int rb = row >> 6, r64 = row & 63;
        int ps = lane >> 2, quad4 = lane & 3;
        *(uint4*)(Q2 + (((size_t)(rb*16 + ps)*4 + quad4)*64 + r64)*8) = qu.v;
    }
}

// ---------------------------------------------------------------------------
// K1: partial[k][n][w] (fp16) = H[n,k] * sum_p Q[n,p] V[k,p,w]
// Block = 128 thr (2 waves), tile 64 rows x 128 w, one k. Grid = mb*65 + kb
// (2080 blocks, 8/CU, lb(128,4) -> 16 waves/CU). Round-robin dispatch puts
// kb = g (mod 8) on XCD g: per-XCD B set ~0.5 MB -> L2-resident; all mb of a
// kb share the XCD. Direct global frag loads, no main-loop barriers.
// Epilogue: wave-private LDS transpose -> dense 128B stores, nontemporal.
// ---------------------------------------------------------------------------
__global__ __launch_bounds__(128, 4)
void k_main(const unsigned short* __restrict__ Q2, const unsigned short* __restrict__ Vt2,
            const float* __restrict__ Ht, unsigned short* __restrict__ partial, int N)
{
    __shared__ __align__(16) unsigned short Es[2][16*66];   // 4.2 KB
    int kb = blockIdx.x % 65;
    int mb = blockIdx.x / 65;

    int tid  = threadIdx.x;
    int lane = tid & 63, wv = tid >> 6;
    int quad = lane >> 4, l16 = lane & 15;
    int rowbase = mb * 64;
    int wbase = wv * 64;

    const unsigned short* aroot = Q2  + (size_t)mb*32768 + quad*512  + l16*8;
    const unsigned short* broot = Vt2 + (size_t)kb*65536 + quad*1024 + (wbase + l16)*8;

    v4f acc[4][4];
    #pragma unroll
    for (int m=0;m<4;++m)
      #pragma unroll
      for (int n=0;n<4;++n)
        #pragma unroll
        for (int r=0;r<4;++r) acc[m][n][r] = 0.f;

    #pragma unroll 4
    for (int ps = 0; ps < 16; ++ps){
        const unsigned short* ap = aroot + ps*2048;
        const unsigned short* bp = broot + ps*4096;
        v8bf a[4], bb[4];
        #pragma unroll
        for (int m=0;m<4;++m) a[m]  = *(const v8bf*)(ap + m*128);
        #pragma unroll
        for (int n=0;n<4;++n) bb[n] = *(const v8bf*)(bp + n*128);
        #pragma unroll
        for (int m=0;m<4;++m)
          #pragma unroll
          for (int n=0;n<4;++n)
            acc[m][n] = __builtin_amdgcn_mfma_f32_16x16x32_bf16(a[m], bb[n], acc[m][n], 0, 0, 0);
    }

    // fold H, stage in wave-private LDS (no barrier), dense nt stores
    const float* hp = Ht + (size_t)kb*N + rowbase + quad*4;
    unsigned short* my = Es[wv];
    unsigned short* gp = partial + (size_t)kb*N*128 + (size_t)rowbase*128 + wbase;
    #pragma unroll
    for (int m = 0; m < 4; ++m){
        v4f hv = *(const v4f*)(hp + m*16);
        #pragma unroll
        for (int n = 0; n < 4; ++n)
          #pragma unroll
          for (int r = 0; r < 4; ++r)
            my[(quad*4 + r)*66 + n*16 + l16] = f2h(hv[r]*acc[m][n][r]);
        #pragma unroll
        for (int jj = 0; jj < 2; ++jj){
            int idx = lane*2 + jj;
            int rr = idx >> 3, cc = idx & 7;
            v4u v = *(const v4u*)(Es[wv] + rr*66 + cc*8);
            __builtin_nontemporal_store(v, (v4u*)(gp + (size_t)(m*16 + rr)*128 + cc*8));
        }
    }
}

// ---------------------------------------------------------------------------
// K2: reduce 65 fp16 slices + LayerNorm(128) -> lnf bf16. 4 rows/block,
// 128 thr: thread owns (row = t>>5, w = (t&31)*4). Dense nt 8B loads.
// ---------------------------------------------------------------------------
__global__ __launch_bounds__(128)
void k_red(const unsigned short* __restrict__ partial, const float* __restrict__ g,
           const float* __restrict__ b, unsigned short* __restrict__ lnf, int N)
{
    int t = threadIdx.x;
    int row0 = blockIdx.x * 4;
    int rl = t >> 5, w = (t & 31)*4;
    int row = row0 + rl;

    const unsigned short* p0 = partial + (size_t)row*128 + w;
    float s0=0.f, s1=0.f, s2=0.f, s3=0.f;
    #pragma unroll
    for (int sl = 0; sl < 65; ++sl){
        union { v2u u; v4h h; } cv;
        cv.u = __builtin_nontemporal_load((const v2u*)(p0 + (size_t)sl*N*128));
        s0 += (float)cv.h[0]; s1 += (float)cv.h[1]; s2 += (float)cv.h[2]; s3 += (float)cv.h[3];
    }
    float sum = s0+s1+s2+s3;
    float sq  = s0*s0+s1*s1+s2*s2+s3*s3;
    #pragma unroll
    for (int off=16; off>0; off>>=1){
        sum += __shfl_xor(sum, off, 32);
        sq  += __shfl_xor(sq,  off, 32);
    }
    float mu  = sum * (1.f/128.f);
    float var = sq * (1.f/128.f) - mu*mu;
    float inv = rsqrtf(var + EPS);
    unsigned short o[4];
    o[0] = f2bf((s0-mu)*inv*g[w+0] + b[w+0]);
    o[1] = f2bf((s1-mu)*inv*g[w+1] + b[w+1]);
    o[2] = f2bf((s2-mu)*inv*g[w+2] + b[w+2]);
    o[3] = f2bf((s3-mu)*inv*g[w+3] + b[w+3]);
    *(uint2*)(lnf + (size_t)row*128 + w) = *(uint2*)o;
}

// ---------------------------------------------------------------------------
// K3: out[n] = silu(lnf @ om_w1) @ om_w2 + om_b2. 32 blocks x 64 rows,
// 4 waves, wave wv owns j-range [wv*128, +128): 4x8 MFMA tiles. LDS reduce.
// ---------------------------------------------------------------------------
__global__ __launch_bounds__(256)
void k_mlp2(const unsigned short* __restrict__ lnf, const unsigned short* __restrict__ w1t,
            const float* __restrict__ w2, const float* __restrict__ b2,
            float* __restrict__ out, int N)
{
    __shared__ float red2[4][64];
    int tid = threadIdx.x, lane = tid & 63, wv = tid >> 6;
    int quad = lane >> 4, l16 = lane & 15;
    int rowbase = blockIdx.x * 64;
    int jbase = wv * 128;

    v4f acc[4][8];
    #pragma unroll
    for (int m=0;m<4;++m)
      #pragma unroll
      for (int n=0;n<8;++n)
        #pragma unroll
        for (int r=0;r<4;++r) acc[m][n][r] = 0.f;

    #pragma unroll
    for (int ps = 0; ps < 4; ++ps){
        v8bf a[4], bb[8];
        #pragma unroll
        for (int m=0;m<4;++m)
            a[m]  = *(const v8bf*)(lnf + (size_t)(rowbase + m*16 + l16)*128 + ps*32 + quad*8);
        #pragma unroll
        for (int n=0;n<8;++n)
            bb[n] = *(const v8bf*)(w1t + (size_t)(jbase + n*16 + l16)*128 + ps*32 + quad*8);
        #pragma unroll
        for (int m=0;m<4;++m)
          #pragma unroll
          for (int n=0;n<8;++n)
            acc[m][n] = __builtin_amdgcn_mfma_f32_16x16x32_bf16(a[m], bb[n], acc[m][n], 0, 0, 0);
    }

    float w2v[8];
    #pragma unroll
    for (int n=0;n<8;++n) w2v[n] = w2[jbase + n*16 + l16];

    #pragma unroll
    for (int m=0;m<4;++m){
        #pragma unroll
        for (int r=0;r<4;++r){
            float s = 0.f;
            #pragma unroll
            for (int n=0;n<8;++n){
                float v = acc[m][n][r];
                s += (v / (1.f + expf(-v))) * w2v[n];
            }
            #pragma unroll
            for (int off=8; off>0; off>>=1) s += __shfl_xor(s, off, 16);
            if (l16 == 0) red2[wv][m*16 + quad*4 + r] = s;
        }
    }
    __syncthreads();
    if (tid < 64)
        out[rowbase + tid] = red2[0][tid] + red2[1][tid] + red2[2][tid] + red2[3][tid] + b2[0];
}

// ---------------------------------------------------------------------------
extern "C" void kernel_launch(void* const* d_in, const int* in_sizes, int n_in,
                              void* d_out, int out_size, void* d_ws, size_t ws_size,
                              hipStream_t stream)
{
    const float* x     = (const float*)d_in[0];
    const float* we_g  = (const float*)d_in[1];
    const float* we_b  = (const float*)d_in[2];
    const float* we_w1 = (const float*)d_in[3];
    const float* we_w2 = (const float*)d_in[4];
    const float* we_b2 = (const float*)d_in[5];
    const float* om_g  = (const float*)d_in[6];
    const float* om_b  = (const float*)d_in[7];
    const float* om_w1 = (const float*)d_in[8];
    const float* om_w2 = (const float*)d_in[9];
    const float* om_b2 = (const float*)d_in[10];

    int N  = in_sizes[0] / 64;     // 2048

    char* ws = (char*)d_ws;
    size_t offV = 0;
    size_t szV  = (size_t)65*16*4*128*8*2;       // 8,519,680
    size_t offQ = offV + szV;
    size_t szQ  = (size_t)N*512*2;               // 2 MB
    size_t offH = offQ + szQ;
    size_t szH  = (size_t)65*N*4;
    size_t offP = offH + szH;
    size_t szP  = (size_t)65*N*128*2;            // 34 MB fp16
    size_t offL = offP + szP;
    size_t szL  = (size_t)N*128*2;
    size_t offW = offL + szL;                    // +128 KB

    unsigned short* Vt2 = (unsigned short*)(ws + offV);
    unsigned short* Q2  = (unsigned short*)(ws + offQ);
    float* Ht           = (float*)(ws + offH);
    unsigned short* Par = (unsigned short*)(ws + offP);
    unsigned short* Lnf = (unsigned short*)(ws + offL);
    unsigned short* W1t = (unsigned short*)(ws + offW);
    float* out = (float*)d_out;

    hipLaunchKernelGGL(k_pre,  dim3(264 + N/4), dim3(256), 0, stream,
                       we_w2, we_b2, Vt2, om_w1, W1t, x, we_g, we_b, we_w1, Q2, Ht, N);
    hipLaunchKernelGGL(k_main, dim3(32*65),     dim3(128), 0, stream, Q2, Vt2, Ht, Par, N);
    hipLaunchKernelGGL(k_red,  dim3(N/4),       dim3(128), 0, stream, Par, om_g, om_b, Lnf, N);
    hipLaunchKernelGGL(k_mlp2, dim3(N/64),      dim3(256), 0, stream, Lnf, W1t, om_w2, om_b2, out, N);
}

// Round 9
// 151.548 us; speedup vs baseline: 1.1217x; 1.0022x over previous
//
#include <hip/hip_runtime.h>
#include <hip/hip_bf16.h>
#include <cstdint>

#define EPS 1e-5f
#define PATH_COEFF 0.04419417382415922f   // 1/sqrt(512)
#define CG110     0.5773502691896258f     // 1/sqrt(3)

typedef __bf16 v8bf __attribute__((ext_vector_type(8)));
typedef float  v4f  __attribute__((ext_vector_type(4)));
typedef _Float16 v4h __attribute__((ext_vector_type(4)));
typedef unsigned int v4u __attribute__((ext_vector_type(4)));
typedef unsigned int v2u __attribute__((ext_vector_type(2)));

static __device__ __forceinline__ unsigned short f2bf(float x){
    unsigned int u = __builtin_bit_cast(unsigned int, x);
    u += 0x7fffu + ((u >> 16) & 1u);      // RNE
    return (unsigned short)(u >> 16);
}
static __device__ __forceinline__ unsigned short f2h(float x){
    return __builtin_bit_cast(unsigned short, (_Float16)x);
}

// ---------------------------------------------------------------------------
// K0: fused prep. blocks [0,260): we_w2/we_b2 -> Vt2 frag-major (8KB LDS);
// [260,264): om_w1 -> w1t bf16 transpose; [264,776): per-row prep, wave/row.
// ---------------------------------------------------------------------------
__global__ __launch_bounds__(256)
void k_pre(const float* __restrict__ w2, const float* __restrict__ b2,
           unsigned short* __restrict__ Vt2,
           const float* __restrict__ om_w1, unsigned short* __restrict__ w1t,
           const float* __restrict__ x, const float* __restrict__ lng,
           const float* __restrict__ lnb, const float* __restrict__ we_w1,
           unsigned short* __restrict__ Q2, float* __restrict__ Ht, int N)
{
    __shared__ __align__(16) unsigned short tile[32][128];   // 8 KB
    int b = blockIdx.x;
    int t = threadIdx.x;

    if (b < 260){
        // ---- convV: Vt2[k][ps16][quad4][w128][8p] bf16 ----
        int k    = b >> 2;
        int slab = b & 3;
        const float* srcbase = (k < 64) ? (w2 + (size_t)k * 65536) : b2;
        for (int chunk = 0; chunk < 4; ++chunk){
            int pbase = slab*128 + chunk*32;
            #pragma unroll
            for (int i = 0; i < 4; ++i){
                int g = t + 256*i;
                int ploc = g >> 5, c4 = g & 31;
                const float4 v = *(const float4*)(srcbase + (size_t)(pbase + ploc)*128 + c4*4);
                unsigned int w0 = (unsigned)f2bf(v.x) | ((unsigned)f2bf(v.y) << 16);
                unsigned int w1 = (unsigned)f2bf(v.z) | ((unsigned)f2bf(v.w) << 16);
                *(uint2*)&tile[ploc][c4*4] = make_uint2(w0, w1);
            }
            __syncthreads();
            int w = t & 127, h = t >> 7;
            int ps = slab*4 + chunk;
            unsigned int words[8];
            #pragma unroll
            for (int g2 = 0; g2 < 8; ++g2)
                words[g2] = (unsigned)tile[h*16 + g2*2][w] | ((unsigned)tile[h*16 + g2*2 + 1][w] << 16);
            unsigned short* dq0 = Vt2 + (((size_t)(k*16 + ps)*4 + 2*h    )*128 + w)*8;
            unsigned short* dq1 = Vt2 + (((size_t)(k*16 + ps)*4 + 2*h + 1)*128 + w)*8;
            *(uint4*)dq0 = make_uint4(words[0], words[1], words[2], words[3]);
            *(uint4*)dq1 = make_uint4(words[4], words[5], words[6], words[7]);
            __syncthreads();
        }
    } else if (b < 264){
        // ---- convW: w1t[j512][w128] bf16 = om_w1[w][j] ----
        int j0 = (b - 260) * 128;
        for (int chunk = 0; chunk < 4; ++chunk){
            #pragma unroll
            for (int i = 0; i < 4; ++i){
                int g = t + 256*i;
                int wloc = g >> 5, c4 = g & 31;
                int w = chunk*32 + wloc;
                const float4 v = *(const float4*)(om_w1 + (size_t)w*512 + j0 + c4*4);
                unsigned int a = (unsigned)f2bf(v.x) | ((unsigned)f2bf(v.y) << 16);
                unsigned int bb = (unsigned)f2bf(v.z) | ((unsigned)f2bf(v.w) << 16);
                *(uint2*)&tile[wloc][c4*4] = make_uint2(a, bb);
            }
            __syncthreads();
            int jl = t & 127, h = t >> 7;
            unsigned int words[8];
            #pragma unroll
            for (int g2 = 0; g2 < 8; ++g2)
                words[g2] = (unsigned)tile[h*16 + g2*2][jl] | ((unsigned)tile[h*16 + g2*2 + 1][jl] << 16);
            unsigned short* dst = w1t + (size_t)(j0 + jl)*128 + chunk*32 + h*16;
            *(uint4*)dst       = make_uint4(words[0], words[1], words[2], words[3]);
            *(uint4*)(dst + 8) = make_uint4(words[4], words[5], words[6], words[7]);
            __syncthreads();
        }
    } else {
        // ---- prep: wave per row, 4 rows/block ----
        int wv = t >> 6, lane = t & 63;
        int row = (b - 264)*4 + wv;
        const float* xr = x + (size_t)row * 64;
        float f[16]; float mu = 0.f;
        #pragma unroll
        for (int u = 0; u < 16; ++u){ f[u] = xr[u]; mu += f[u]; }
        mu *= (1.f/16.f);
        float var = 0.f;
        #pragma unroll
        for (int u = 0; u < 16; ++u){ float d = f[u] - mu; var += d*d; }
        var *= (1.f/16.f);
        float inv = rsqrtf(var + EPS);
        float lnf[16];
        #pragma unroll
        for (int u = 0; u < 16; ++u) lnf[u] = (f[u]-mu)*inv*lng[u] + lnb[u];
        float h1 = 0.f;
        #pragma unroll
        for (int u = 0; u < 16; ++u) h1 += lnf[u] * we_w1[u*64 + lane];
        float h = h1 / (1.f + expf(-h1));
        Ht[(size_t)lane * N + row] = h;
        if (lane == 0) Ht[(size_t)64 * N + row] = 1.f;

        union { unsigned short qs[8]; uint4 v; } qu;
        #pragma unroll
        for (int j = 0; j < 8; ++j){
            int p = lane*8 + j;
            float q;
            if (p < 256){
                int u = p >> 4, v = p & 15;
                q = PATH_COEFF * f[u] * f[v];
            } else {
                int pp = p - 256;
                int u = pp >> 4, v = pp & 15;
                const float* ya = xr + 16 + u*3;
                const float* yb = xr + 16 + v*3;
                q = (PATH_COEFF * CG110) * (ya[0]*yb[0] + ya[1]*yb[1] + ya[2]*yb[2]);
            }
            qu.qs[j] = f2bf(q);
        }
        int rb = row >> 6, r64 = row & 63;
        int ps = lane >> 2, quad4 = lane & 3;
        *(uint4*)(Q2 + (((size_t)(rb*16 + ps)*4 + quad4)*64 + r64)*8) = qu.v;
    }
}

// ---------------------------------------------------------------------------
// K1: partial[k][n][w] (fp16) = H[n,k] * sum_p Q[n,p] V[k,p,w]
// Block 256 thr = 4 waves (2x2), tile 128x128, one k. Grid mb*65+kb (1040).
// B: wave-private double-buffered LDS staging (4KB/ps chunk), NO barriers —
// a wave only reads what it wrote; lgkmcnt ordering suffices. Prefetch for
// ps+1 issued before compute of ps, ds_write after (hides global latency).
// A: direct global (Q2 2MB, L2-hot in every XCD).
// LDS 32KB/block -> 4 blocks/CU at lb(256,4) = 16 waves/CU.
// Epilogue: reuse LDS for wave-private transpose -> dense 128B nt stores.
// ---------------------------------------------------------------------------
__global__ __launch_bounds__(256, 4)
void k_main(const unsigned short* __restrict__ Q2, const unsigned short* __restrict__ Vt2,
            const float* __restrict__ Ht, unsigned short* __restrict__ partial, int N)
{
    __shared__ __align__(16) unsigned short Bs[4][2][2048];   // 32 KB
    int kb = blockIdx.x % 65;
    int mb = blockIdx.x / 65;

    int tid  = threadIdx.x;
    int lane = tid & 63, wv = tid >> 6;
    int r2 = wv >> 1, c2 = wv & 1;
    int quad = lane >> 4, l16 = lane & 15;
    int rowbase = mb*128 + r2*64;
    int rb = rowbase >> 6;
    int wbase = c2*64;

    const unsigned short* aroot = Q2  + (size_t)rb*32768 + quad*512 + l16*8;
    const unsigned short* broot = Vt2 + (size_t)kb*65536 + wbase*8;   // +ps*4096 +r*1024, lane*8

    v4f acc[4][4];
    #pragma unroll
    for (int m=0;m<4;++m)
      #pragma unroll
      for (int n=0;n<4;++n)
        #pragma unroll
        for (int r=0;r<4;++r) acc[m][n][r] = 0.f;

    unsigned short* bs0 = &Bs[wv][0][0];
    unsigned short* bs1 = &Bs[wv][1][0];

    // prologue: stage ps=0
    {
        v4u br[4];
        #pragma unroll
        for (int r=0;r<4;++r) br[r] = *(const v4u*)(broot + r*1024 + lane*8);
        #pragma unroll
        for (int r=0;r<4;++r) *(v4u*)(bs0 + r*512 + lane*8) = br[r];
    }

    #pragma unroll 2
    for (int ps = 0; ps < 16; ++ps){
        unsigned short* cur = (ps & 1) ? bs1 : bs0;
        unsigned short* nxt = (ps & 1) ? bs0 : bs1;
        v4u nb[4];
        if (ps < 15){
            const unsigned short* bp = broot + (ps+1)*4096;
            #pragma unroll
            for (int r=0;r<4;++r) nb[r] = *(const v4u*)(bp + r*1024 + lane*8);
        }
        const unsigned short* ap = aroot + ps*2048;
        v8bf a[4], bb[4];
        #pragma unroll
        for (int m=0;m<4;++m) a[m] = *(const v8bf*)(ap + m*128);
        #pragma unroll
        for (int n=0;n<4;++n) bb[n] = *(const v8bf*)(cur + quad*512 + (n*16 + l16)*8);
        #pragma unroll
        for (int m=0;m<4;++m)
          #pragma unroll
          for (int n=0;n<4;++n)
            acc[m][n] = __builtin_amdgcn_mfma_f32_16x16x32_bf16(a[m], bb[n], acc[m][n], 0, 0, 0);
        if (ps < 15){
            #pragma unroll
            for (int r=0;r<4;++r) *(v4u*)(nxt + r*512 + lane*8) = nb[r];
        }
    }

    // epilogue: fold H, wave-private transpose in (now-free) Bs, dense nt stores
    const float* hp = Ht + (size_t)kb*N + rowbase + quad*4;
    unsigned short* Es = &Bs[wv][0][0];      // 16 rows x 66 pitch = 2.1 KB
    unsigned short* gp = partial + (size_t)kb*N*128 + (size_t)rowbase*128 + wbase;
    #pragma unroll
    for (int m = 0; m < 4; ++m){
        v4f hv = *(const v4f*)(hp + m*16);
        #pragma unroll
        for (int n = 0; n < 4; ++n)
          #pragma unroll
          for (int r = 0; r < 4; ++r)
            Es[(quad*4 + r)*66 + n*16 + l16] = f2h(hv[r]*acc[m][n][r]);
        #pragma unroll
        for (int jj = 0; jj < 2; ++jj){
            int idx = lane*2 + jj;
            int rr = idx >> 3, cc = idx & 7;
            v4u v = *(const v4u*)(Es + rr*66 + cc*8);
            __builtin_nontemporal_store(v, (v4u*)(gp + (size_t)(m*16 + rr)*128 + cc*8));
        }
    }
}

// ---------------------------------------------------------------------------
// K2: reduce 65 fp16 slices + LayerNorm(128) -> lnf bf16. 4 rows/block,
// 128 thr: thread owns (row = t>>5, w = (t&31)*4). Dense nt 8B loads.
// ---------------------------------------------------------------------------
__global__ __launch_bounds__(128)
void k_red(const unsigned short* __restrict__ partial, const float* __restrict__ g,
           const float* __restrict__ b, unsigned short* __restrict__ lnf, int N)
{
    int t = threadIdx.x;
    int row0 = blockIdx.x * 4;
    int rl = t >> 5, w = (t & 31)*4;
    int row = row0 + rl;

    const unsigned short* p0 = partial + (size_t)row*128 + w;
    float s0=0.f, s1=0.f, s2=0.f, s3=0.f;
    #pragma unroll
    for (int sl = 0; sl < 65; ++sl){
        union { v2u u; v4h h; } cv;
        cv.u = __builtin_nontemporal_load((const v2u*)(p0 + (size_t)sl*N*128));
        s0 += (float)cv.h[0]; s1 += (float)cv.h[1]; s2 += (float)cv.h[2]; s3 += (float)cv.h[3];
    }
    float sum = s0+s1+s2+s3;
    float sq  = s0*s0+s1*s1+s2*s2+s3*s3;
    #pragma unroll
    for (int off=16; off>0; off>>=1){
        sum += __shfl_xor(sum, off, 32);
        sq  += __shfl_xor(sq,  off, 32);
    }
    float mu  = sum * (1.f/128.f);
    float var = sq * (1.f/128.f) - mu*mu;
    float inv = rsqrtf(var + EPS);
    unsigned short o[4];
    o[0] = f2bf((s0-mu)*inv*g[w+0] + b[w+0]);
    o[1] = f2bf((s1-mu)*inv*g[w+1] + b[w+1]);
    o[2] = f2bf((s2-mu)*inv*g[w+2] + b[w+2]);
    o[3] = f2bf((s3-mu)*inv*g[w+3] + b[w+3]);
    *(uint2*)(lnf + (size_t)row*128 + w) = *(uint2*)o;
}

// ---------------------------------------------------------------------------
// K3: out[n] = silu(lnf @ om_w1) @ om_w2 + om_b2. 32 blocks x 64 rows,
// 4 waves, wave wv owns j-range [wv*128, +128): 4x8 MFMA tiles. LDS reduce.
// ---------------------------------------------------------------------------
__global__ __launch_bounds__(256)
void k_mlp2(const unsigned short* __restrict__ lnf, const unsigned short* __restrict__ w1t,
            const float* __restrict__ w2, const float* __restrict__ b2,
            float* __restrict__ out, int N)
{
    __shared__ float red2[4][64];
    int tid = threadIdx.x, lane = tid & 63, wv = tid >> 6;
    int quad = lane >> 4, l16 = lane & 15;
    int rowbase = blockIdx.x * 64;
    int jbase = wv * 128;

    v4f acc[4][8];
    #pragma unroll
    for (int m=0;m<4;++m)
      #pragma unroll
      for (int n=0;n<8;++n)
        #pragma unroll
        for (int r=0;r<4;++r) acc[m][n][r] = 0.f;

    #pragma unroll
    for (int ps = 0; ps < 4; ++ps){
        v8bf a[4], bb[8];
        #pragma unroll
        for (int m=0;m<4;++m)
            a[m]  = *(const v8bf*)(lnf + (size_t)(rowbase + m*16 + l16)*128 + ps*32 + quad*8);
        #pragma unroll
        for (int n=0;n<8;++n)
            bb[n] = *(const v8bf*)(w1t + (size_t)(jbase + n*16 + l16)*128 + ps*32 + quad*8);
        #pragma unroll
        for (int m=0;m<4;++m)
          #pragma unroll
          for (int n=0;n<8;++n)
            acc[m][n] = __builtin_amdgcn_mfma_f32_16x16x32_bf16(a[m], bb[n], acc[m][n], 0, 0, 0);
    }

    float w2v[8];
    #pragma unroll
    for (int n=0;n<8;++n) w2v[n] = w2[jbase + n*16 + l16];

    #pragma unroll
    for (int m=0;m<4;++m){
        #pragma unroll
        for (int r=0;r<4;++r){
            float s = 0.f;
            #pragma unroll
            for (int n=0;n<8;++n){
                float v = acc[m][n][r];
                s += (v / (1.f + expf(-v))) * w2v[n];
            }
            #pragma unroll
            for (int off=8; off>0; off>>=1) s += __shfl_xor(s, off, 16);
            if (l16 == 0) red2[wv][m*16 + quad*4 + r] = s;
        }
    }
    __syncthreads();
    if (tid < 64)
        out[rowbase + tid] = red2[0][tid] + red2[1][tid] + red2[2][tid] + red2[3][tid] + b2[0];
}

// ---------------------------------------------------------------------------
extern "C" void kernel_launch(void* const* d_in, const int* in_sizes, int n_in,
                              void* d_out, int out_size, void* d_ws, size_t ws_size,
                              hipStream_t stream)
{
    const float* x     = (const float*)d_in[0];
    const float* we_g  = (const float*)d_in[1];
    const float* we_b  = (const float*)d_in[2];
    const float* we_w1 = (const float*)d_in[3];
    const float* we_w2 = (const float*)d_in[4];
    const float* we_b2 = (const float*)d_in[5];
    const float* om_g  = (const float*)d_in[6];
    const float* om_b  = (const float*)d_in[7];
    const float* om_w1 = (const float*)d_in[8];
    const float* om_w2 = (const float*)d_in[9];
    const float* om_b2 = (const float*)d_in[10];

    int N  = in_sizes[0] / 64;     // 2048

    char* ws = (char*)d_ws;
    size_t offV = 0;
    size_t szV  = (size_t)65*16*4*128*8*2;       // 8,519,680
    size_t offQ = offV + szV;
    size_t szQ  = (size_t)N*512*2;               // 2 MB
    size_t offH = offQ + szQ;
    size_t szH  = (size_t)65*N*4;
    size_t offP = offH + szH;
    size_t szP  = (size_t)65*N*128*2;            // 34 MB fp16
    size_t offL = offP + szP;
    size_t szL  = (size_t)N*128*2;
    size_t offW = offL + szL;                    // +128 KB

    unsigned short* Vt2 = (unsigned short*)(ws + offV);
    unsigned short* Q2  = (unsigned short*)(ws + offQ);
    float* Ht           = (float*)(ws + offH);
    unsigned short* Par = (unsigned short*)(ws + offP);
    unsigned short* Lnf = (unsigned short*)(ws + offL);
    unsigned short* W1t = (unsigned short*)(ws + offW);
    float* out = (float*)d_out;

    hipLaunchKernelGGL(k_pre,  dim3(264 + N/4), dim3(256), 0, stream,
                       we_w2, we_b2, Vt2, om_w1, W1t, x, we_g, we_b, we_w1, Q2, Ht, N);
    hipLaunchKernelGGL(k_main, dim3(16*65),     dim3(256), 0, stream, Q2, Vt2, Ht, Par, N);
    hipLaunchKernelGGL(k_red,  dim3(N/4),       dim3(128), 0, stream, Par, om_g, om_b, Lnf, N);
    hipLaunchKernelGGL(k_mlp2, dim3(N/64),      dim3(256), 0, stream, Lnf, W1t, om_w2, om_b2, out, N);
}